// Round 10
// baseline (485.487 us; speedup 1.0000x reference)
//
#include <hip/hip_runtime.h>

typedef float f32x2 __attribute__((ext_vector_type(2)));

#define IMG_W 512
#define IMG_H 512
#define TY 8
#define PLANES 96              // N*C = 32*3
#define NPIX (32ll * 3 * 512 * 512)
#define NACC 64                // atomic fanout slots
#define NBLOCKS (64 * PLANES)  // 6144

// Separable Gaussian, sigma=1.5, size=11, normalized (compile-time folded).
#define WG_INIT { 0.00102838f, 0.00759876f, 0.03600077f, 0.10936069f, \
                  0.21300553f, 0.26601172f, 0.21300553f, 0.10936069f, \
                  0.03600077f, 0.00759876f, 0.00102838f }

// ===== Consolidated best structure (measured 84.6us main) =====
// 4 maps {p, t, p^2+t^2, p*t} (sigma1+sigma2 fused via conv linearity).
// 512 threads; vertical pass: 1 col/thread, 18 rows -> 4 packed row-pairs;
// horizontal pass: W=4 cols/thread, 2 map-phases through 8 static slabs
// (34.8 KB -> 4 blocks/CU; cross-block phase interleave is the overlap
// mechanism). HARD CONSTRAINTS (all measured, do not revisit):
//  - VGPR < 64      (R6/R8-rolling: 72-108 VGPR -> occupancy collapse)
//  - static LDS <= ~35 KB (R7 dynamic-LDS -> scratch disaster; R11 64 KB
//    static -> residency collapse, 300us)
//  - no asm pk-fma  (R6: fewer insts but lost sched freedom -> +10us)
//  - keep 2 phases  (single-phase falsified both ways)
//
// DS model (validated R3-R5): wave b128 read = 4 inherent "conflict" cyc
// (half rate), b64 writes free with pmap. pmap bank-group(at) =
// ((at>>1)&7)^((at&1)<<2): conflict-free for stride-2 cross-lane b128 reads
// AND stride-1 b64 writes. Expect SQ_LDS_BANK_CONFLICT == 6291456 exactly.
//
// R12: + last-block fused finalization (proven in R8/R11) -- drops the
// separate ssim_final dispatch.
#define SLAB_ATOMS 272
#define SLAB_BYTES (SLAB_ATOMS * 16)

__device__ __forceinline__ int pmap(int at) {
    const int par = at & 1;
    return (at & ~15) | (par << 3) | (((at >> 1) & 7) ^ (par << 2));
}

__global__ __launch_bounds__(512)   // NO min-waves arg (R2: forced spill)
void ssim_main(const float* __restrict__ pred, const float* __restrict__ targ,
               double* __restrict__ acc, float* __restrict__ out) {
    const float WG[11] = WG_INIT;

    __shared__ __align__(16) unsigned char ldsraw[8 * SLAB_BYTES];
    __shared__ float wsum[8];
    __shared__ int islast;

    const int tid   = threadIdx.x;
    const int x     = tid;                 // column owned in vertical pass
    const int plane = blockIdx.y;
    const int y0    = blockIdx.x * TY;
    const size_t base = (size_t)plane * (IMG_W * IMG_H);
    const float* pCol = pred + base + x;
    const float* tCol = targ + base + x;

    // Zero horizontal halo pads: atoms 0..3 and 260..263 in each of 8 slabs.
    // Data writes never touch them; they stay zero across both phases.
    if (tid < 64) {
        const int s   = tid >> 3;               // slab 0..7
        const int idx = tid & 7;                // 0..7
        const int at  = (idx < 4) ? idx : (256 + idx);   // 0..3 / 260..263
        *(float4*)(ldsraw + s * SLAB_BYTES + pmap(at) * 16) =
            (float4){0.f, 0.f, 0.f, 0.f};
    }

    // ---- vertical pass: 18 rows -> 8 output rows as 4 packed row-pairs ----
    float pv[TY + 10], tv[TY + 10];
#pragma unroll
    for (int iy = 0; iy < TY + 10; ++iy) {
        const int y = y0 - 5 + iy;
        pv[iy] = 0.f; tv[iy] = 0.f;
        if ((unsigned)y < (unsigned)IMG_H) {    // wave-uniform
            pv[iy] = pCol[(size_t)y * IMG_W];
            tv[iy] = tCol[(size_t)y * IMG_W];
        }
    }

    f32x2 A[4][4];
#pragma unroll
    for (int m = 0; m < 4; ++m)
#pragma unroll
        for (int rp = 0; rp < 4; ++rp) A[m][rp] = (f32x2){0.f, 0.f};

#pragma unroll
    for (int iy = 0; iy < TY + 10; ++iy) {
        const float p = pv[iy], t = tv[iy];
        const float ss = __builtin_fmaf(t, t, p * p);   // p^2 + t^2
        const float pt = p * t;
        const f32x2 vs[4] = { {p,p}, {t,t}, {ss,ss}, {pt,pt} };
#pragma unroll
        for (int rp = 0; rp < 4; ++rp) {
            const int a = iy - 2 * rp;                      // compile-time
            if (a < 0 || a > 11) continue;                  // both lanes zero
            const float w0 = (a <= 10) ? WG[a] : 0.f;       // row 2rp
            const float w1 = (a >= 1)  ? WG[a - 1] : 0.f;   // row 2rp+1
            const f32x2 w = (f32x2){w0, w1};
#pragma unroll
            for (int m = 0; m < 4; ++m)
                A[m][rp] = __builtin_elementwise_fma(vs[m], w, A[m][rp]);
        }
    }

    // ---- horizontal pass: thread (rpl, g) -> out cols 4g..4g+3, row-pair rpl
    const int g   = tid & 127;         // col group
    const int rpl = tid >> 7;          // 0..3: row-pair slab this thread reads
    // write address: entry c = x+8
    const int wat = (x + 8) >> 1;
    const int wof = pmap(wat) * 16 + ((x + 8) & 1) * 8;
    // read addresses: atoms 2g+1..2g+8 -> entries 4g+2..4g+17 (win[0..15]);
    // out col 4g+c needs entries 4g+c+3..4g+c+13 = win[c+1..c+11]
    int rof[8];
#pragma unroll
    for (int q = 0; q < 8; ++q) rof[q] = pmap(2 * g + 1 + q) * 16;

    f32x2 H[4][4];   // [map][col]
#pragma unroll
    for (int phase = 0; phase < 2; ++phase) {
        if (phase) __syncthreads();   // phase-0 reads done before overwrite
#pragma unroll
        for (int ml = 0; ml < 2; ++ml)
#pragma unroll
            for (int rp = 0; rp < 4; ++rp)
                *(f32x2*)(ldsraw + (ml * 4 + rp) * SLAB_BYTES + wof) =
                    A[phase * 2 + ml][rp];
        __syncthreads();              // also covers pad-zero init (phase 0)

#pragma unroll
        for (int ml = 0; ml < 2; ++ml) {
            const unsigned char* slab = ldsraw + (ml * 4 + rpl) * SLAB_BYTES;
            f32x2 win[16];
#pragma unroll
            for (int q = 0; q < 8; ++q) {
                const float4 v = *(const float4*)(slab + rof[q]);
                win[2 * q]     = (f32x2){v.x, v.y};
                win[2 * q + 1] = (f32x2){v.z, v.w};
            }
            f32x2 hacc[4];
#pragma unroll
            for (int c = 0; c < 4; ++c) hacc[c] = (f32x2){0.f, 0.f};
#pragma unroll
            for (int k = 0; k < 11; ++k) {
                const f32x2 wk = (f32x2){WG[k], WG[k]};
#pragma unroll
                for (int c = 0; c < 4; ++c)
                    hacc[c] = __builtin_elementwise_fma(win[c + 1 + k], wk,
                                                        hacc[c]);
            }
#pragma unroll
            for (int c = 0; c < 4; ++c) H[phase * 2 + ml][c] = hacc[c];
        }
    }

    // ---- SSIM on 4 cols x 2 rows ----
    const float C1 = 1e-4f, C2 = 9e-4f;
    float lsum = 0.f;
#pragma unroll
    for (int c = 0; c < 4; ++c) {
        const f32x2 mu1 = H[0][c], mu2 = H[1][c];
        const f32x2 S   = H[2][c], P  = H[3][c];
        const f32x2 mu12 = mu1 * mu2;
        const f32x2 musq = mu1 * mu1 + mu2 * mu2;
        // num = (2*mu1mu2 + C1) * (2*sigma12 + C2), sigma12 = P - mu12
        const f32x2 num = (mu12 + mu12 + (f32x2){C1, C1}) *
                          ((P - mu12) + (P - mu12) + (f32x2){C2, C2});
        // den = (musq + C1) * (S - musq + C2) + 1e-8
        const f32x2 den = (musq + (f32x2){C1, C1}) *
                          (S - musq + (f32x2){C2, C2}) + (f32x2){1e-8f, 1e-8f};
        lsum += num.x * __builtin_amdgcn_rcpf(den.x);
        lsum += num.y * __builtin_amdgcn_rcpf(den.y);
    }

    // ---- reduction: wave shuffle -> LDS -> one atomic per block ----
#pragma unroll
    for (int off = 32; off > 0; off >>= 1)
        lsum += __shfl_down(lsum, off);
    if ((tid & 63) == 0) wsum[tid >> 6] = lsum;
    __syncthreads();
    unsigned int* cnt = (unsigned int*)(acc + NACC);
    if (tid == 0) {
        float s = 0.f;
#pragma unroll
        for (int i = 0; i < 8; ++i) s += wsum[i];
        atomicAdd(&acc[blockIdx.x & (NACC - 1)], (double)s);
        __threadfence();                   // acc add visible before cnt
        const unsigned int old = atomicAdd(cnt, 1u);
        islast = (old == NBLOCKS - 1);
    }
    __syncthreads();

    // ---- fused finalization by the last block (proven R8/R11) ----
    if (islast && tid < 64) {
        __threadfence();
        double v = atomicAdd(&acc[tid], 0.0);   // device-coherent read
#pragma unroll
        for (int off = 32; off > 0; off >>= 1)
            v += __shfl_down(v, off);
        if (tid == 0)
            out[0] = 1.0f - (float)(v * (1.0 / (double)NPIX));
    }
}

extern "C" void kernel_launch(void* const* d_in, const int* in_sizes, int n_in,
                              void* d_out, int out_size, void* d_ws, size_t ws_size,
                              hipStream_t stream) {
    const float* pred = (const float*)d_in[0];
    const float* targ = (const float*)d_in[1];
    double* acc = (double*)d_ws;

    // zero acc slots + last-block counter
    hipMemsetAsync(acc, 0, (NACC + 1) * sizeof(double), stream);

    dim3 grid(IMG_H / TY, PLANES);   // adjacent strips -> halo L2 reuse
    ssim_main<<<grid, 512, 0, stream>>>(pred, targ, acc, (float*)d_out);
}

// Round 12
// 227.298 us; speedup vs baseline: 2.1359x; 2.1359x over previous
//
#include <hip/hip_runtime.h>

typedef float f32x2 __attribute__((ext_vector_type(2)));

#define IMG_W 512
#define IMG_H 512
#define TY 8
#define PLANES 96              // N*C = 32*3
#define NPIX (32ll * 3 * 512 * 512)
#define NACC 64                // atomic fanout slots

// Separable Gaussian, sigma=1.5, size=11, normalized (compile-time folded).
#define WG_INIT { 0.00102838f, 0.00759876f, 0.03600077f, 0.10936069f, \
                  0.21300553f, 0.26601172f, 0.21300553f, 0.10936069f, \
                  0.03600077f, 0.00759876f, 0.00102838f }

// ===== Session-verified optimum (222.57us total / 84.6us main) =====
// 4 maps {p, t, p^2+t^2, p*t} (sigma1+sigma2 fused via conv linearity).
// 512 threads; vertical: 1 col/thread, 18 rows -> 4 packed row-pairs;
// horizontal: W=4 cols/thread, 2 map-phases through 8 static slabs
// (34.8 KB -> 4 blocks/CU; cross-block phase interleave IS the overlap
// mechanism). HARD CONSTRAINTS (all measured this session, do not revisit):
//  - VGPR < 64        (R6/R8: 72-108 VGPR -> occupancy collapse)
//  - static LDS ~35KB (R7 dynamic-LDS -> scratch disaster 14.9ms;
//                      R11 64KB static -> residency collapse 300us)
//  - no asm pk-fma    (R6: fewer insts, lost sched freedom -> +10us)
//  - keep 2 phases    (single-phase falsified both directions)
//  - NO fused finalization (R12: per-block __threadfence = device-scope
//    L2 writeback on non-coherent XCDs -> ~270us stall at 6144 blocks)
//
// DS model (validated R3-R5): wave b128 read = 4 inherent "conflict" cyc
// (half rate vs 128B/cyc banks); b64 writes free under pmap. pmap
// bank-group(at) = ((at>>1)&7)^((at&1)<<2): conflict-free for stride-2
// cross-lane b128 reads AND stride-1 b64 writes.
// SQ_LDS_BANK_CONFLICT == 6291456 exactly (inherent only, 0 real).
#define SLAB_ATOMS 272
#define SLAB_BYTES (SLAB_ATOMS * 16)

__device__ __forceinline__ int pmap(int at) {
    const int par = at & 1;
    return (at & ~15) | (par << 3) | (((at >> 1) & 7) ^ (par << 2));
}

__global__ __launch_bounds__(512)   // NO min-waves arg (R2: forced spill)
void ssim_main(const float* __restrict__ pred, const float* __restrict__ targ,
               double* __restrict__ acc) {
    const float WG[11] = WG_INIT;

    __shared__ __align__(16) unsigned char ldsraw[8 * SLAB_BYTES];
    __shared__ float wsum[8];

    const int tid   = threadIdx.x;
    const int x     = tid;                 // column owned in vertical pass
    const int plane = blockIdx.y;
    const int y0    = blockIdx.x * TY;
    const size_t base = (size_t)plane * (IMG_W * IMG_H);
    const float* pCol = pred + base + x;
    const float* tCol = targ + base + x;

    // Zero horizontal halo pads: atoms 0..3 and 260..263 in each of 8 slabs.
    // Data writes never touch them; they stay zero across both phases.
    if (tid < 64) {
        const int s   = tid >> 3;               // slab 0..7
        const int idx = tid & 7;                // 0..7
        const int at  = (idx < 4) ? idx : (256 + idx);   // 0..3 / 260..263
        *(float4*)(ldsraw + s * SLAB_BYTES + pmap(at) * 16) =
            (float4){0.f, 0.f, 0.f, 0.f};
    }

    // ---- vertical pass: 18 rows -> 8 output rows as 4 packed row-pairs ----
    float pv[TY + 10], tv[TY + 10];
#pragma unroll
    for (int iy = 0; iy < TY + 10; ++iy) {
        const int y = y0 - 5 + iy;
        pv[iy] = 0.f; tv[iy] = 0.f;
        if ((unsigned)y < (unsigned)IMG_H) {    // wave-uniform
            pv[iy] = pCol[(size_t)y * IMG_W];
            tv[iy] = tCol[(size_t)y * IMG_W];
        }
    }

    f32x2 A[4][4];
#pragma unroll
    for (int m = 0; m < 4; ++m)
#pragma unroll
        for (int rp = 0; rp < 4; ++rp) A[m][rp] = (f32x2){0.f, 0.f};

#pragma unroll
    for (int iy = 0; iy < TY + 10; ++iy) {
        const float p = pv[iy], t = tv[iy];
        const float ss = __builtin_fmaf(t, t, p * p);   // p^2 + t^2
        const float pt = p * t;
        const f32x2 vs[4] = { {p,p}, {t,t}, {ss,ss}, {pt,pt} };
#pragma unroll
        for (int rp = 0; rp < 4; ++rp) {
            const int a = iy - 2 * rp;                      // compile-time
            if (a < 0 || a > 11) continue;                  // both lanes zero
            const float w0 = (a <= 10) ? WG[a] : 0.f;       // row 2rp
            const float w1 = (a >= 1)  ? WG[a - 1] : 0.f;   // row 2rp+1
            const f32x2 w = (f32x2){w0, w1};
#pragma unroll
            for (int m = 0; m < 4; ++m)
                A[m][rp] = __builtin_elementwise_fma(vs[m], w, A[m][rp]);
        }
    }

    // ---- horizontal pass: thread (rpl, g) -> out cols 4g..4g+3, row-pair rpl
    const int g   = tid & 127;         // col group
    const int rpl = tid >> 7;          // 0..3: row-pair slab this thread reads
    // write address: entry c = x+8
    const int wat = (x + 8) >> 1;
    const int wof = pmap(wat) * 16 + ((x + 8) & 1) * 8;
    // read addresses: atoms 2g+1..2g+8 -> entries 4g+2..4g+17 (win[0..15]);
    // out col 4g+c needs entries 4g+c+3..4g+c+13 = win[c+1..c+11]
    int rof[8];
#pragma unroll
    for (int q = 0; q < 8; ++q) rof[q] = pmap(2 * g + 1 + q) * 16;

    f32x2 H[4][4];   // [map][col]
#pragma unroll
    for (int phase = 0; phase < 2; ++phase) {
        if (phase) __syncthreads();   // phase-0 reads done before overwrite
#pragma unroll
        for (int ml = 0; ml < 2; ++ml)
#pragma unroll
            for (int rp = 0; rp < 4; ++rp)
                *(f32x2*)(ldsraw + (ml * 4 + rp) * SLAB_BYTES + wof) =
                    A[phase * 2 + ml][rp];
        __syncthreads();              // also covers pad-zero init (phase 0)

#pragma unroll
        for (int ml = 0; ml < 2; ++ml) {
            const unsigned char* slab = ldsraw + (ml * 4 + rpl) * SLAB_BYTES;
            f32x2 win[16];
#pragma unroll
            for (int q = 0; q < 8; ++q) {
                const float4 v = *(const float4*)(slab + rof[q]);
                win[2 * q]     = (f32x2){v.x, v.y};
                win[2 * q + 1] = (f32x2){v.z, v.w};
            }
            f32x2 hacc[4];
#pragma unroll
            for (int c = 0; c < 4; ++c) hacc[c] = (f32x2){0.f, 0.f};
#pragma unroll
            for (int k = 0; k < 11; ++k) {
                const f32x2 wk = (f32x2){WG[k], WG[k]};
#pragma unroll
                for (int c = 0; c < 4; ++c)
                    hacc[c] = __builtin_elementwise_fma(win[c + 1 + k], wk,
                                                        hacc[c]);
            }
#pragma unroll
            for (int c = 0; c < 4; ++c) H[phase * 2 + ml][c] = hacc[c];
        }
    }

    // ---- SSIM on 4 cols x 2 rows ----
    const float C1 = 1e-4f, C2 = 9e-4f;
    float lsum = 0.f;
#pragma unroll
    for (int c = 0; c < 4; ++c) {
        const f32x2 mu1 = H[0][c], mu2 = H[1][c];
        const f32x2 S   = H[2][c], P  = H[3][c];
        const f32x2 mu12 = mu1 * mu2;
        const f32x2 musq = mu1 * mu1 + mu2 * mu2;
        // num = (2*mu1mu2 + C1) * (2*sigma12 + C2), sigma12 = P - mu12
        const f32x2 num = (mu12 + mu12 + (f32x2){C1, C1}) *
                          ((P - mu12) + (P - mu12) + (f32x2){C2, C2});
        // den = (musq + C1) * (S - musq + C2) + 1e-8
        const f32x2 den = (musq + (f32x2){C1, C1}) *
                          (S - musq + (f32x2){C2, C2}) + (f32x2){1e-8f, 1e-8f};
        lsum += num.x * __builtin_amdgcn_rcpf(den.x);
        lsum += num.y * __builtin_amdgcn_rcpf(den.y);
    }

    // ---- reduction: wave shuffle -> LDS -> one atomic per block (64 slots) ----
#pragma unroll
    for (int off = 32; off > 0; off >>= 1)
        lsum += __shfl_down(lsum, off);
    if ((tid & 63) == 0) wsum[tid >> 6] = lsum;
    __syncthreads();
    if (tid == 0) {
        float s = 0.f;
#pragma unroll
        for (int i = 0; i < 8; ++i) s += wsum[i];
        atomicAdd(&acc[blockIdx.x & (NACC - 1)], (double)s);
    }
}

__global__ void ssim_final(const double* __restrict__ acc, float* __restrict__ out) {
    const int i = threadIdx.x;           // 64 threads
    double s = acc[i];
#pragma unroll
    for (int off = 32; off > 0; off >>= 1)
        s += __shfl_down(s, off);
    if (i == 0) out[0] = 1.0f - (float)(s * (1.0 / (double)NPIX));
}

extern "C" void kernel_launch(void* const* d_in, const int* in_sizes, int n_in,
                              void* d_out, int out_size, void* d_ws, size_t ws_size,
                              hipStream_t stream) {
    const float* pred = (const float*)d_in[0];
    const float* targ = (const float*)d_in[1];
    double* acc = (double*)d_ws;

    hipMemsetAsync(acc, 0, NACC * sizeof(double), stream);

    dim3 grid(IMG_H / TY, PLANES);   // adjacent strips -> halo L2 reuse
    ssim_main<<<grid, 512, 0, stream>>>(pred, targ, acc);
    ssim_final<<<1, 64, 0, stream>>>(acc, (float*)d_out);
}